// Round 7
// baseline (511.311 us; speedup 1.0000x reference)
//
#include <hip/hip_runtime.h>
#include <cstdint>
#include <cstddef>

// ---------------------------------------------------------------------------
// R7: - k_gemm_big replaced by k_gemm_fp: the R5 k_step structure scaled up.
//       32x64 tile per wave, frag-packed B (coalesced 1KB wave-loads, no LDS,
//       no barriers), direct-register A loads, depth-2 prefetch. Grid 16x88
//       x4 waves = 5632 waves (vs 704 in R5/R6 -> the 9% occupancy fix).
//     - All weights packed to MFMA B-fragment order by one kernel (z=0..4);
//       [n][k] transposes removed.
//     - k_step reverted to R5 verbatim (435us config; R6's XCD remap lost).
// ---------------------------------------------------------------------------

typedef _Float16 half8 __attribute__((ext_vector_type(8)));
typedef float floatx4 __attribute__((ext_vector_type(4)));

__device__ __forceinline__ float sigmoidf_(float x) {
  return 1.f / (1.f + __expf(-x));
}

// ---- pack fp32 src [K][N] into MFMA B-fragment order f16 chunks:
// chunk (nt,kcG): 4KB = [j 0..3][lane 0..63][8 halves];
// value at n = nt*64 + j*16 + (lane&15), k = kcG*32 + (lane>>4)*8 + u.
// z=0: w_pp->Wrf kOff0 | z=1: w_cp->Wrf kOff32 (K=512) | z=2: w_pc->Wcf (N=512)
// z=3: w_oh->Wohf | z=4: w_hp->Whpf
__global__ __launch_bounds__(256) void k_pack_all(
    const float* __restrict__ w_pp, const float* __restrict__ w_cp,
    const float* __restrict__ w_pc, const float* __restrict__ w_oh,
    const float* __restrict__ w_hp, _Float16* __restrict__ Wrf,
    _Float16* __restrict__ Wcf, _Float16* __restrict__ Wohf,
    _Float16* __restrict__ Whpf) {
  const int z = blockIdx.z;
  const float* src;
  _Float16* dst;
  int N, kStride, kOff;
  switch (z) {
    case 0: src = w_pp; dst = Wrf;  N = 1024; kStride = 48; kOff = 0;  break;
    case 1: if (blockIdx.y >= 8) return;
            src = w_cp; dst = Wrf;  N = 1024; kStride = 48; kOff = 32; break;
    case 2: if (blockIdx.x >= 8) return;
            src = w_pc; dst = Wcf;  N = 512;  kStride = 32; kOff = 0;  break;
    case 3: src = w_oh; dst = Wohf; N = 1024; kStride = 32; kOff = 0;  break;
    default:src = w_hp; dst = Whpf; N = 1024; kStride = 32; kOff = 0;  break;
  }
  __shared__ float tile[64][65];
  const int k0 = blockIdx.y * 64, n0 = blockIdx.x * 64;
  const int tx = threadIdx.x & 63, ty = threadIdx.x >> 6;
#pragma unroll
  for (int jj = 0; jj < 16; ++jj) {
    int kr = jj * 4 + ty;
    tile[kr][tx] = src[(size_t)(k0 + kr) * N + n0 + tx];
  }
  __syncthreads();
  const int j = threadIdx.x >> 6, lane = threadIdx.x & 63;
  const int r16 = lane & 15, quad = lane >> 4;
#pragma unroll
  for (int c = 0; c < 2; ++c) {
    half8 v;
#pragma unroll
    for (int u = 0; u < 8; ++u)
      v[u] = (_Float16)tile[c * 32 + quad * 8 + u][j * 16 + r16];
    const int kcG = kOff + blockIdx.y * 2 + c;
    *(half8*)(dst + ((size_t)(blockIdx.x * kStride + kcG) * 4 + j) * 512 +
              lane * 8) = v;
  }
}

// ---- Q_0 = 0.25*(0.5*colsum(w_hp) + bias_p), broadcast over batch
__global__ __launch_bounds__(256) void k_q0(
    const float* __restrict__ w_hp, const float* __restrict__ bias_p,
    _Float16* __restrict__ Q) {
  const int n = blockIdx.x * 256 + threadIdx.x;  // 0..1023
  float s = 0.f;
  for (int k = 0; k < 1024; ++k) s += w_hp[(size_t)k * 1024 + n];
  const _Float16 q = (_Float16)(0.25f * (0.5f * s + bias_p[n]));
  for (int b = 0; b < 1024; ++b) Q[(size_t)b * 1024 + n] = q;
}

// ---- prefix scan over t of x (decay 0.75) -> U f16 [11][1024][1024]; inits
__global__ __launch_bounds__(256) void k_prep(
    const float* __restrict__ x, _Float16* __restrict__ U,
    _Float16* __restrict__ AP0, _Float16* __restrict__ AC0,
    float* __restrict__ Pst, float* __restrict__ Cst) {
  const int id = blockIdx.x * 256 + threadIdx.x;  // 0 .. 1M-1
  const int b = id >> 10, i = id & 1023;
  const float* xb = x + (size_t)b * 12 * 1024 + i;
  float g = 0.f;
#pragma unroll
  for (int t = 0; t < 11; ++t) {
    g = xb[t * 1024] + 0.75f * g;
    U[(size_t)t * 1048576 + id] = (_Float16)g;
  }
  AP0[id] = (_Float16)0.5f;
  Pst[id] = 0.f;
  if (i < 512) {
    const int cid = b * 512 + i;
    AC0[cid] = (_Float16)0.5f;
    Cst[cid] = 0.f;
  }
}

// ---- big GEMM, K=1024: 32x64 tile per wave, frag-packed B, no LDS/barriers.
// Grid (16 n-tiles, 88); block = 4 independent waves (m subtiles).
// mode 0: oh -> AH[t]: sigmoid(0.25*acc + beta*bias_h), rows offset +1024
// mode 1: hp -> Q: 0.25*(acc + bias_p)
__global__ __launch_bounds__(256, 3) void k_gemm_fp(
    const _Float16* __restrict__ A, const _Float16* __restrict__ Bf,
    const float* __restrict__ bias, _Float16* __restrict__ dst, int mode) {
  const int lane = threadIdx.x & 63, w = threadIdx.x >> 6;
  const int r16 = lane & 15, quad = lane >> 4;
  const int mBase = (blockIdx.y * 4 + w) * 32;
  const int nt = blockIdx.x;
  const floatx4 zero = {0.f, 0.f, 0.f, 0.f};
  floatx4 acc[2][4];
#pragma unroll
  for (int i = 0; i < 2; ++i)
#pragma unroll
    for (int j = 0; j < 4; ++j) acc[i][j] = zero;

  const _Float16* A0 = A + (size_t)(mBase + r16) * 1024 + quad * 8;
  const _Float16* A1 = A0 + 16 * 1024;
  const _Float16* wb = Bf + (size_t)nt * 32 * 2048 + lane * 8;

  half8 ab[3][2], bb[3][4];
  auto LD = [&](int c, int buf) {
    const int kg = c * 32;
    ab[buf][0] = *(const half8*)(A0 + kg);
    ab[buf][1] = *(const half8*)(A1 + kg);
    const _Float16* wp = wb + (size_t)c * 2048;
#pragma unroll
    for (int j = 0; j < 4; ++j) bb[buf][j] = *(const half8*)(wp + j * 512);
  };
  auto MM = [&](int buf) {
#pragma unroll
    for (int i = 0; i < 2; ++i)
#pragma unroll
      for (int j = 0; j < 4; ++j)
        acc[i][j] = __builtin_amdgcn_mfma_f32_16x16x32_f16(
            ab[buf][i], bb[buf][j], acc[i][j], 0, 0, 0);
  };

  LD(0, 0);
  LD(1, 1);
#pragma unroll
  for (int c = 0; c < 32; ++c) {
    if (c + 2 < 32) LD(c + 2, (c + 2) % 3);
    MM(c % 3);
  }

  if (mode == 0) {
    const int t = (mBase >> 10) + 1;  // 32-row tiles never straddle t bounds
    const float beta = 1.f - __powf(0.75f, (float)t);
    _Float16* o = dst + (size_t)(mBase + 1024) * 1024;
#pragma unroll
    for (int i = 0; i < 2; ++i)
#pragma unroll
      for (int j = 0; j < 4; ++j) {
        const int n = nt * 64 + j * 16 + r16;
#pragma unroll
        for (int r = 0; r < 4; ++r) {
          const int row = i * 16 + quad * 4 + r;
          const float h = 0.25f * acc[i][j][r] + beta * bias[n];
          o[(size_t)row * 1024 + n] = (_Float16)sigmoidf_(h);
        }
      }
  } else {
    _Float16* o = dst + (size_t)mBase * 1024;
#pragma unroll
    for (int i = 0; i < 2; ++i)
#pragma unroll
      for (int j = 0; j < 4; ++j) {
        const int n = nt * 64 + j * 16 + r16;
#pragma unroll
        for (int r = 0; r < 4; ++r) {
          const int row = i * 16 + quad * 4 + r;
          o[(size_t)row * 1024 + n] = (_Float16)(0.25f * (acc[i][j][r] + bias[n]));
        }
      }
  }
}

// ---- one recurrent step (R5 verbatim): 4-wave split-K, LDS reduce.
// blocks 0..511:  P 32m x 64n, K=1536 (12 chunks/wave) over [a_p|a_c]
// blocks 512..767: C 32m x 64n, K=1024 (8 chunks/wave) over a_p
__global__ __launch_bounds__(256, 3) void k_step(
    const _Float16* __restrict__ Qt, const _Float16* __restrict__ APc,
    const _Float16* __restrict__ ACc, _Float16* __restrict__ APn,
    _Float16* __restrict__ ACn, const _Float16* __restrict__ Wrf,
    const _Float16* __restrict__ Wcf, const float* __restrict__ bias_c,
    float* __restrict__ Pst, float* __restrict__ Cst,
    float* __restrict__ out_t) {
  __shared__ float red[4][2][4][4][64];  // 32 KB
  const int lane = threadIdx.x & 63, w = threadIdx.x >> 6;
  const int r16 = lane & 15, quad = lane >> 4;
  const int blk = blockIdx.x;
  const bool isP = blk < 512;
  int mBase, nt;
  if (isP) {
    mBase = (blk >> 4) * 32;
    nt = blk & 15;
  } else {
    const int b = blk - 512;
    mBase = (b >> 3) * 32;
    nt = b & 7;
  }
  const int nBase = nt * 64;
  const floatx4 zero = {0.f, 0.f, 0.f, 0.f};
  floatx4 acc[2][4];
#pragma unroll
  for (int i = 0; i < 2; ++i)
#pragma unroll
    for (int j = 0; j < 4; ++j) acc[i][j] = zero;

  half8 abuf[3][2], bbuf[3][4];
  auto MM = [&](half8* af, half8* bf) {
#pragma unroll
    for (int i = 0; i < 2; ++i)
#pragma unroll
      for (int j = 0; j < 4; ++j)
        acc[i][j] = __builtin_amdgcn_mfma_f32_16x16x32_f16(af[i], bf[j],
                                                           acc[i][j], 0, 0, 0);
  };

  if (isP) {
    const int kcBase = w * 12;
    auto LD = [&](half8* af, half8* bf, int c) {
      const int kc = kcBase + c;
      const int kg = kc * 32;
      if (kc < 32) {
#pragma unroll
        for (int i = 0; i < 2; ++i)
          af[i] = *(const half8*)(APc + (size_t)(mBase + i * 16 + r16) * 1024 +
                                  kg + quad * 8);
      } else {
#pragma unroll
        for (int i = 0; i < 2; ++i)
          af[i] = *(const half8*)(ACc + (size_t)(mBase + i * 16 + r16) * 512 +
                                  (kg - 1024) + quad * 8);
      }
      const _Float16* wp = Wrf + (size_t)(nt * 48 + kc) * 2048 + lane * 8;
#pragma unroll
      for (int j = 0; j < 4; ++j) bf[j] = *(const half8*)(wp + j * 512);
    };
    LD(abuf[0], bbuf[0], 0);
    LD(abuf[1], bbuf[1], 1);
#pragma unroll
    for (int c = 0; c < 12; ++c) {
      if (c + 2 < 12) LD(abuf[(c + 2) % 3], bbuf[(c + 2) % 3], c + 2);
      MM(abuf[c % 3], bbuf[c % 3]);
    }
  } else {
    const int kcBase = w * 8;
    auto LD = [&](half8* af, half8* bf, int c) {
      const int kc = kcBase + c;
      const int kg = kc * 32;
#pragma unroll
      for (int i = 0; i < 2; ++i)
        af[i] = *(const half8*)(APc + (size_t)(mBase + i * 16 + r16) * 1024 +
                                kg + quad * 8);
      const _Float16* wp = Wcf + (size_t)(nt * 32 + kc) * 2048 + lane * 8;
#pragma unroll
      for (int j = 0; j < 4; ++j) bf[j] = *(const half8*)(wp + j * 512);
    };
    LD(abuf[0], bbuf[0], 0);
    LD(abuf[1], bbuf[1], 1);
#pragma unroll
    for (int c = 0; c < 8; ++c) {
      if (c + 2 < 8) LD(abuf[(c + 2) % 3], bbuf[(c + 2) % 3], c + 2);
      MM(abuf[c % 3], bbuf[c % 3]);
    }
  }

  // cross-wave K reduction
#pragma unroll
  for (int i = 0; i < 2; ++i)
#pragma unroll
    for (int j = 0; j < 4; ++j)
#pragma unroll
      for (int r = 0; r < 4; ++r) red[w][i][j][r][lane] = acc[i][j][r];
  __syncthreads();

  // wave w handles output column group j = w
  if (isP) {
#pragma unroll
    for (int i = 0; i < 2; ++i) {
      const int n = nBase + w * 16 + r16;
#pragma unroll
      for (int r = 0; r < 4; ++r) {
        const float v = red[0][i][w][r][lane] + red[1][i][w][r][lane] +
                        red[2][i][w][r][lane] + red[3][i][w][r][lane];
        const int b = mBase + i * 16 + quad * 4 + r;
        const size_t o = (size_t)b * 1024 + n;
        const float pn = 0.25f * v + (float)Qt[o] + 0.75f * Pst[o];
        Pst[o] = pn;
        const float a = sigmoidf_(pn);
        APn[o] = (_Float16)a;
        if (out_t) out_t[o] = a;
      }
    }
  } else {
#pragma unroll
    for (int i = 0; i < 2; ++i) {
      const int n = nBase + w * 16 + r16;  // 0..511
#pragma unroll
      for (int r = 0; r < 4; ++r) {
        const float v = red[0][i][w][r][lane] + red[1][i][w][r][lane] +
                        red[2][i][w][r][lane] + red[3][i][w][r][lane];
        const int b = mBase + i * 16 + quad * 4 + r;
        const size_t o = (size_t)b * 512 + n;
        const float cn = 0.25f * (v + bias_c[n]) + 0.75f * Cst[o];
        Cst[o] = cn;
        ACn[o] = (_Float16)sigmoidf_(cn);
      }
    }
  }
}

extern "C" void kernel_launch(void* const* d_in, const int* in_sizes, int n_in,
                              void* d_out, int out_size, void* d_ws,
                              size_t ws_size, hipStream_t stream) {
  const float* x      = (const float*)d_in[0];  // [1024,12,1024]
  const float* w_oh   = (const float*)d_in[1];
  const float* w_hp   = (const float*)d_in[2];
  const float* w_pp   = (const float*)d_in[3];  // [k][n]
  const float* w_pc   = (const float*)d_in[4];  // [1024,512]
  const float* w_cp   = (const float*)d_in[5];  // [512,1024]
  const float* bias_h = (const float*)d_in[6];
  const float* bias_p = (const float*)d_in[7];
  const float* bias_c = (const float*)d_in[8];
  float* out = (float*)d_out;

  uint8_t* p = (uint8_t*)d_ws;
  _Float16* Wrf  = (_Float16*)p; p += (size_t)1024 * 1536 * 2;  // frag-packed
  _Float16* Wcf  = (_Float16*)p; p += (size_t)512 * 1024 * 2;
  _Float16* Wohf = (_Float16*)p; p += (size_t)1024 * 1024 * 2;
  _Float16* Whpf = (_Float16*)p; p += (size_t)1024 * 1024 * 2;
  _Float16* U    = (_Float16*)p; p += (size_t)11 * 1048576 * 2;
  _Float16* AH   = (_Float16*)p; p += (size_t)12 * 1048576 * 2;
  _Float16* Q    = (_Float16*)p; p += (size_t)12 * 1048576 * 2;
  _Float16* AP0  = (_Float16*)p; p += (size_t)1048576 * 2;
  _Float16* AP1  = (_Float16*)p; p += (size_t)1048576 * 2;
  _Float16* AC0  = (_Float16*)p; p += (size_t)512 * 1024 * 2;
  _Float16* AC1  = (_Float16*)p; p += (size_t)512 * 1024 * 2;
  float* Pst = (float*)p; p += (size_t)1048576 * 4;
  float* Cst = (float*)p; p += (size_t)512 * 1024 * 4;

  const dim3 blk256(256);
  k_pack_all<<<dim3(16, 16, 5), blk256, 0, stream>>>(w_pp, w_cp, w_pc, w_oh,
                                                     w_hp, Wrf, Wcf, Wohf, Whpf);
  k_q0<<<dim3(4), blk256, 0, stream>>>(w_hp, bias_p, Q);
  k_prep<<<4096, blk256, 0, stream>>>(x, U, AP0, AC0, Pst, Cst);
  // hoisted h GEMM -> AH[1..11]  (M=11264)
  k_gemm_fp<<<dim3(16, 88), blk256, 0, stream>>>(U, Wohf, bias_h, AH, 0);
  // hoisted hp GEMM: Q_t = 0.25*(a_h_t @ w_hp + bias_p), t=1..11
  k_gemm_fp<<<dim3(16, 88), blk256, 0, stream>>>(AH + 1048576, Whpf, bias_p,
                                                 Q + 1048576, 1);
  // 12 sequential steps
  for (int t = 0; t < 12; ++t) {
    const _Float16* APc = (t & 1) ? AP1 : AP0;
    _Float16* APn       = (t & 1) ? AP0 : AP1;
    const _Float16* ACc = (t & 1) ? AC1 : AC0;
    _Float16* ACn       = (t & 1) ? AC0 : AC1;
    float* ot = (t >= 8) ? out + (size_t)(t - 8) * 1048576 : (float*)nullptr;
    k_step<<<dim3(768), blk256, 0, stream>>>(Q + (size_t)t * 1048576, APc,
                                             ACc, APn, ACn, Wrf, Wcf, bias_c,
                                             Pst, Cst, ot);
  }
}

// Round 8
// 457.471 us; speedup vs baseline: 1.1177x; 1.1177x over previous
//
#include <hip/hip_runtime.h>
#include <cstdint>
#include <cstddef>

// ---------------------------------------------------------------------------
// R8: manual software pipeline via inline-asm loads + explicit vmcnt waits.
// R7's compiler-scheduled register prefetch was collapsed (VGPR_Count=44 ->
// loads sunk to use, depth-0). Here:
//  - global_load_dwordx4 issued by asm volatile (waitcnt pass ignores asm, no
//    auto-drain), 4 rotating register buffers, depth-3 prefetch,
//    s_waitcnt vmcnt(12/6/0) asm with loaded regs tied as "+v" operands so
//    consumers can't be hoisted above the wait.
//  - hot loops contain no compiler vector loads (its own vmcnt accounting
//    only starts after our final vmcnt(0)).
//  - applied to k_gemm_fp (32 chunks) and k_step P/C (12/8 chunks).
//  - k_q0 split: 16-block column-sum; broadcast folded into k_prep.
// ---------------------------------------------------------------------------

typedef _Float16 half8 __attribute__((ext_vector_type(8)));
typedef float floatx4 __attribute__((ext_vector_type(4)));

__device__ __forceinline__ float sigmoidf_(float x) {
  return 1.f / (1.f + __expf(-x));
}

__device__ __forceinline__ void gld(half8& d, const _Float16* p) {
  asm volatile("global_load_dwordx4 %0, %1, off" : "=v"(d) : "v"(p) : "memory");
}
__device__ __forceinline__ void gldo(half8& d, const _Float16* p, int boff) {
  asm volatile("global_load_dwordx4 %0, %1, off offset:%2"
               : "=v"(d) : "v"(p), "n"(boff) : "memory");
}

// ---- pack fp32 src [K][N] into MFMA B-fragment order f16 chunks:
// chunk (nt,kcG): 4KB = [j 0..3][lane 0..63][8 halves];
// n = nt*64 + j*16 + (lane&15), k = kcG*32 + (lane>>4)*8 + u.
__global__ __launch_bounds__(256) void k_pack_all(
    const float* __restrict__ w_pp, const float* __restrict__ w_cp,
    const float* __restrict__ w_pc, const float* __restrict__ w_oh,
    const float* __restrict__ w_hp, _Float16* __restrict__ Wrf,
    _Float16* __restrict__ Wcf, _Float16* __restrict__ Wohf,
    _Float16* __restrict__ Whpf) {
  const int z = blockIdx.z;
  const float* src;
  _Float16* dst;
  int N, kStride, kOff;
  switch (z) {
    case 0: src = w_pp; dst = Wrf;  N = 1024; kStride = 48; kOff = 0;  break;
    case 1: if (blockIdx.y >= 8) return;
            src = w_cp; dst = Wrf;  N = 1024; kStride = 48; kOff = 32; break;
    case 2: if (blockIdx.x >= 8) return;
            src = w_pc; dst = Wcf;  N = 512;  kStride = 32; kOff = 0;  break;
    case 3: src = w_oh; dst = Wohf; N = 1024; kStride = 32; kOff = 0;  break;
    default:src = w_hp; dst = Whpf; N = 1024; kStride = 32; kOff = 0;  break;
  }
  __shared__ float tile[64][65];
  const int k0 = blockIdx.y * 64, n0 = blockIdx.x * 64;
  const int tx = threadIdx.x & 63, ty = threadIdx.x >> 6;
#pragma unroll
  for (int jj = 0; jj < 16; ++jj) {
    int kr = jj * 4 + ty;
    tile[kr][tx] = src[(size_t)(k0 + kr) * N + n0 + tx];
  }
  __syncthreads();
  const int j = threadIdx.x >> 6, lane = threadIdx.x & 63;
  const int r16 = lane & 15, quad = lane >> 4;
#pragma unroll
  for (int c = 0; c < 2; ++c) {
    half8 v;
#pragma unroll
    for (int u = 0; u < 8; ++u)
      v[u] = (_Float16)tile[c * 32 + quad * 8 + u][j * 16 + r16];
    const int kcG = kOff + blockIdx.y * 2 + c;
    *(half8*)(dst + ((size_t)(blockIdx.x * kStride + kcG) * 4 + j) * 512 +
              lane * 8) = v;
  }
}

// ---- q0[n] = 0.25*(0.5*colsum(w_hp) + bias_p[n]); 16 blocks
__global__ __launch_bounds__(256) void k_q0sum(
    const float* __restrict__ w_hp, const float* __restrict__ bias_p,
    float* __restrict__ q0) {
  __shared__ float part[4][64];
  const int n = blockIdx.x * 64 + (threadIdx.x & 63);
  const int seg = threadIdx.x >> 6;
  float s = 0.f;
  for (int k = seg * 256; k < seg * 256 + 256; ++k)
    s += w_hp[(size_t)k * 1024 + n];
  part[seg][threadIdx.x & 63] = s;
  __syncthreads();
  if (seg == 0) {
    const float t =
        part[0][threadIdx.x] + part[1][threadIdx.x] + part[2][threadIdx.x] +
        part[3][threadIdx.x];
    q0[n] = 0.25f * (0.5f * t + bias_p[n]);
  }
}

// ---- prefix scan of x (decay 0.75) -> U; init AP0/AC0/Pst/Cst; Q0 broadcast
__global__ __launch_bounds__(256) void k_prep(
    const float* __restrict__ x, _Float16* __restrict__ U,
    _Float16* __restrict__ AP0, _Float16* __restrict__ AC0,
    float* __restrict__ Pst, float* __restrict__ Cst,
    const float* __restrict__ q0, _Float16* __restrict__ Q) {
  const int id = blockIdx.x * 256 + threadIdx.x;  // 0 .. 1M-1
  const int b = id >> 10, i = id & 1023;
  const float* xb = x + (size_t)b * 12 * 1024 + i;
  float g = 0.f;
#pragma unroll
  for (int t = 0; t < 11; ++t) {
    g = xb[t * 1024] + 0.75f * g;
    U[(size_t)t * 1048576 + id] = (_Float16)g;
  }
  AP0[id] = (_Float16)0.5f;
  Pst[id] = 0.f;
  Q[id] = (_Float16)q0[i];
  if (i < 512) {
    const int cid = b * 512 + i;
    AC0[cid] = (_Float16)0.5f;
    Cst[cid] = 0.f;
  }
}

#define GWAIT(NSTR, B)                                                  \
  asm volatile("s_waitcnt vmcnt(" NSTR ")"                              \
               : "+v"(ab[B][0]), "+v"(ab[B][1]), "+v"(bb[B][0]),        \
                 "+v"(bb[B][1]), "+v"(bb[B][2]), "+v"(bb[B][3]))

// ---- big GEMM, K=1024: 32x64 tile/wave, frag-packed B, manual asm pipeline.
// Grid (16 n-tiles, 88); block = 4 independent waves (m subtiles).
// mode 0: oh -> AH[t]: sigmoid(0.25*acc + beta*bias_h), rows offset +1024
// mode 1: hp -> Q: 0.25*(acc + bias_p)
__global__ __launch_bounds__(256, 3) void k_gemm_fp(
    const _Float16* __restrict__ A, const _Float16* __restrict__ Bf,
    const float* __restrict__ bias, _Float16* __restrict__ dst, int mode) {
  const int lane = threadIdx.x & 63, w = threadIdx.x >> 6;
  const int r16 = lane & 15, quad = lane >> 4;
  const int mBase = (blockIdx.y * 4 + w) * 32;
  const int nt = blockIdx.x;
  const floatx4 zero = {0.f, 0.f, 0.f, 0.f};
  floatx4 acc[2][4];
#pragma unroll
  for (int i = 0; i < 2; ++i)
#pragma unroll
    for (int j = 0; j < 4; ++j) acc[i][j] = zero;

  const _Float16* A0 = A + (size_t)(mBase + r16) * 1024 + quad * 8;
  const _Float16* A1 = A0 + 16 * 1024;
  const _Float16* wb = Bf + (size_t)nt * 32 * 2048 + lane * 8;

  half8 ab[4][2], bb[4][4];
  auto LDC = [&](int c, int buf) {  // c is a compile-time constant (unrolled)
    gldo(ab[buf][0], A0, c * 64);
    gldo(ab[buf][1], A1, c * 64);
    const _Float16* wp = wb + (size_t)c * 2048;
    gldo(bb[buf][0], wp, 0);
    gldo(bb[buf][1], wp, 1024);
    gldo(bb[buf][2], wp, 2048);
    gldo(bb[buf][3], wp, 3072);
  };
  auto MM = [&](int buf) {
#pragma unroll
    for (int i = 0; i < 2; ++i)
#pragma unroll
      for (int j = 0; j < 4; ++j)
        acc[i][j] = __builtin_amdgcn_mfma_f32_16x16x32_f16(
            ab[buf][i], bb[buf][j], acc[i][j], 0, 0, 0);
  };

  LDC(0, 0);
  LDC(1, 1);
  LDC(2, 2);
#pragma unroll
  for (int c = 0; c < 32; ++c) {
    const int buf = c & 3;
    if (c <= 32 - 3) GWAIT("12", buf);
    else if (c == 32 - 2) GWAIT("6", buf);
    else GWAIT("0", buf);
    if (c + 3 < 32) LDC(c + 3, (c + 3) & 3);
    MM(buf);
  }
  asm volatile("s_waitcnt vmcnt(0)" ::: "memory");

  if (mode == 0) {
    const int t = (mBase >> 10) + 1;  // 32-row tiles never straddle t bounds
    const float beta = 1.f - __powf(0.75f, (float)t);
    _Float16* o = dst + (size_t)(mBase + 1024) * 1024;
#pragma unroll
    for (int i = 0; i < 2; ++i)
#pragma unroll
      for (int j = 0; j < 4; ++j) {
        const int n = nt * 64 + j * 16 + r16;
#pragma unroll
        for (int r = 0; r < 4; ++r) {
          const int row = i * 16 + quad * 4 + r;
          const float h = 0.25f * acc[i][j][r] + beta * bias[n];
          o[(size_t)row * 1024 + n] = (_Float16)sigmoidf_(h);
        }
      }
  } else {
    _Float16* o = dst + (size_t)mBase * 1024;
#pragma unroll
    for (int i = 0; i < 2; ++i)
#pragma unroll
      for (int j = 0; j < 4; ++j) {
        const int n = nt * 64 + j * 16 + r16;
#pragma unroll
        for (int r = 0; r < 4; ++r) {
          const int row = i * 16 + quad * 4 + r;
          o[(size_t)row * 1024 + n] = (_Float16)(0.25f * (acc[i][j][r] + bias[n]));
        }
      }
  }
}

// ---- one recurrent step: 4-wave split-K, LDS reduce, manual asm pipeline.
// blocks 0..511:  P 32m x 64n, K=1536 (12 chunks/wave) over [a_p|a_c]
// blocks 512..767: C 32m x 64n, K=1024 (8 chunks/wave) over a_p
__global__ __launch_bounds__(256, 3) void k_step(
    const _Float16* __restrict__ Qt, const _Float16* __restrict__ APc,
    const _Float16* __restrict__ ACc, _Float16* __restrict__ APn,
    _Float16* __restrict__ ACn, const _Float16* __restrict__ Wrf,
    const _Float16* __restrict__ Wcf, const float* __restrict__ bias_c,
    float* __restrict__ Pst, float* __restrict__ Cst,
    float* __restrict__ out_t) {
  __shared__ float red[4][2][4][4][64];  // 32 KB
  const int lane = threadIdx.x & 63, w = threadIdx.x >> 6;
  const int r16 = lane & 15, quad = lane >> 4;
  const int blk = blockIdx.x;
  const bool isP = blk < 512;
  int mBase, nt;
  if (isP) {
    mBase = (blk >> 4) * 32;
    nt = blk & 15;
  } else {
    const int b = blk - 512;
    mBase = (b >> 3) * 32;
    nt = b & 7;
  }
  const int nBase = nt * 64;
  const floatx4 zero = {0.f, 0.f, 0.f, 0.f};
  floatx4 acc[2][4];
#pragma unroll
  for (int i = 0; i < 2; ++i)
#pragma unroll
    for (int j = 0; j < 4; ++j) acc[i][j] = zero;

  const _Float16* Ap0 = APc + (size_t)(mBase + r16) * 1024 + quad * 8;
  const _Float16* Ap1 = Ap0 + 16 * 1024;
  const _Float16* Ac0 = ACc + (size_t)(mBase + r16) * 512 + quad * 8;
  const _Float16* Ac1 = Ac0 + 16 * 512;

  half8 ab[4][2], bb[4][4];
  auto MM = [&](int buf) {
#pragma unroll
    for (int i = 0; i < 2; ++i)
#pragma unroll
      for (int j = 0; j < 4; ++j)
        acc[i][j] = __builtin_amdgcn_mfma_f32_16x16x32_f16(
            ab[buf][i], bb[buf][j], acc[i][j], 0, 0, 0);
  };

  if (isP) {
    const int kcBase = w * 12;
    const _Float16* wbase = Wrf + (size_t)(nt * 48 + kcBase) * 2048 + lane * 8;
    auto LDC = [&](int c, int buf) {
      const int kc = kcBase + c;
      const _Float16 *a0p, *a1p;
      if (kc < 32) {
        a0p = Ap0 + kc * 32;
        a1p = Ap1 + kc * 32;
      } else {
        a0p = Ac0 + (kc - 32) * 32;
        a1p = Ac1 + (kc - 32) * 32;
      }
      gld(ab[buf][0], a0p);
      gld(ab[buf][1], a1p);
      const _Float16* wp = wbase + (size_t)c * 2048;
      gldo(bb[buf][0], wp, 0);
      gldo(bb[buf][1], wp, 1024);
      gldo(bb[buf][2], wp, 2048);
      gldo(bb[buf][3], wp, 3072);
    };
    LDC(0, 0);
    LDC(1, 1);
    LDC(2, 2);
#pragma unroll
    for (int c = 0; c < 12; ++c) {
      const int buf = c & 3;
      if (c <= 12 - 3) GWAIT("12", buf);
      else if (c == 12 - 2) GWAIT("6", buf);
      else GWAIT("0", buf);
      if (c + 3 < 12) LDC(c + 3, (c + 3) & 3);
      MM(buf);
    }
  } else {
    const int kcBase = w * 8;
    const _Float16* wbase = Wcf + (size_t)(nt * 32 + kcBase) * 2048 + lane * 8;
    auto LDC = [&](int c, int buf) {
      const int kc = kcBase + c;
      gld(ab[buf][0], Ap0 + kc * 32);
      gld(ab[buf][1], Ap1 + kc * 32);
      const _Float16* wp = wbase + (size_t)c * 2048;
      gldo(bb[buf][0], wp, 0);
      gldo(bb[buf][1], wp, 1024);
      gldo(bb[buf][2], wp, 2048);
      gldo(bb[buf][3], wp, 3072);
    };
    LDC(0, 0);
    LDC(1, 1);
    LDC(2, 2);
#pragma unroll
    for (int c = 0; c < 8; ++c) {
      const int buf = c & 3;
      if (c <= 8 - 3) GWAIT("12", buf);
      else if (c == 8 - 2) GWAIT("6", buf);
      else GWAIT("0", buf);
      if (c + 3 < 8) LDC(c + 3, (c + 3) & 3);
      MM(buf);
    }
  }
  asm volatile("s_waitcnt vmcnt(0)" ::: "memory");

  // cross-wave K reduction
#pragma unroll
  for (int i = 0; i < 2; ++i)
#pragma unroll
    for (int j = 0; j < 4; ++j)
#pragma unroll
      for (int r = 0; r < 4; ++r) red[w][i][j][r][lane] = acc[i][j][r];
  __syncthreads();

  // wave w handles output column group j = w
  if (isP) {
#pragma unroll
    for (int i = 0; i < 2; ++i) {
      const int n = nBase + w * 16 + r16;
#pragma unroll
      for (int r = 0; r < 4; ++r) {
        const float v = red[0][i][w][r][lane] + red[1][i][w][r][lane] +
                        red[2][i][w][r][lane] + red[3][i][w][r][lane];
        const int b = mBase + i * 16 + quad * 4 + r;
        const size_t o = (size_t)b * 1024 + n;
        const float pn = 0.25f * v + (float)Qt[o] + 0.75f * Pst[o];
        Pst[o] = pn;
        const float a = sigmoidf_(pn);
        APn[o] = (_Float16)a;
        if (out_t) out_t[o] = a;
      }
    }
  } else {
#pragma unroll
    for (int i = 0; i < 2; ++i) {
      const int n = nBase + w * 16 + r16;  // 0..511
#pragma unroll
      for (int r = 0; r < 4; ++r) {
        const float v = red[0][i][w][r][lane] + red[1][i][w][r][lane] +
                        red[2][i][w][r][lane] + red[3][i][w][r][lane];
        const int b = mBase + i * 16 + quad * 4 + r;
        const size_t o = (size_t)b * 512 + n;
        const float cn = 0.25f * (v + bias_c[n]) + 0.75f * Cst[o];
        Cst[o] = cn;
        ACn[o] = (_Float16)sigmoidf_(cn);
      }
    }
  }
}
#undef GWAIT

extern "C" void kernel_launch(void* const* d_in, const int* in_sizes, int n_in,
                              void* d_out, int out_size, void* d_ws,
                              size_t ws_size, hipStream_t stream) {
  const float* x      = (const float*)d_in[0];  // [1024,12,1024]
  const float* w_oh   = (const float*)d_in[1];
  const float* w_hp   = (const float*)d_in[2];
  const float* w_pp   = (const float*)d_in[3];  // [k][n]
  const float* w_pc   = (const float*)d_in[4];  // [1024,512]
  const float* w_cp   = (const float*)d_in[5];  // [512,1024]
  const float* bias_h = (const float*)d_in[6];
  const float* bias_p = (const float*)d_in[7];
  const float* bias_c = (const float*)d_in[8];
  float* out = (float*)d_out;

  uint8_t* p = (uint8_t*)d_ws;
  _Float16* Wrf  = (_Float16*)p; p += (size_t)1024 * 1536 * 2;  // frag-packed
  _Float16* Wcf  = (_Float16*)p; p += (size_t)512 * 1024 * 2;
  _Float16* Wohf = (_Float16*)p; p += (size_t)1024 * 1024 * 2;
  _Float16* Whpf = (_Float16*)p; p += (size_t)1024 * 1024 * 2;
  _Float16* U    = (_Float16*)p; p += (size_t)11 * 1048576 * 2;
  _Float16* AH   = (_Float16*)p; p += (size_t)12 * 1048576 * 2;
  _Float16* Q    = (_Float16*)p; p += (size_t)12 * 1048576 * 2;
  _Float16* AP0  = (_Float16*)p; p += (size_t)1048576 * 2;
  _Float16* AP1  = (_Float16*)p; p += (size_t)1048576 * 2;
  _Float16* AC0  = (_Float16*)p; p += (size_t)512 * 1024 * 2;
  _Float16* AC1  = (_Float16*)p; p += (size_t)512 * 1024 * 2;
  float* Pst = (float*)p; p += (size_t)1048576 * 4;
  float* Cst = (float*)p; p += (size_t)512 * 1024 * 4;
  float* q0  = (float*)p; p += 1024 * 4;

  const dim3 blk256(256);
  k_pack_all<<<dim3(16, 16, 5), blk256, 0, stream>>>(w_pp, w_cp, w_pc, w_oh,
                                                     w_hp, Wrf, Wcf, Wohf, Whpf);
  k_q0sum<<<dim3(16), blk256, 0, stream>>>(w_hp, bias_p, q0);
  k_prep<<<4096, blk256, 0, stream>>>(x, U, AP0, AC0, Pst, Cst, q0, Q);
  // hoisted h GEMM -> AH[1..11]  (M=11264)
  k_gemm_fp<<<dim3(16, 88), blk256, 0, stream>>>(U, Wohf, bias_h, AH, 0);
  // hoisted hp GEMM: Q_t = 0.25*(a_h_t @ w_hp + bias_p), t=1..11
  k_gemm_fp<<<dim3(16, 88), blk256, 0, stream>>>(AH + 1048576, Whpf, bias_p,
                                                 Q + 1048576, 1);
  // 12 sequential steps
  for (int t = 0; t < 12; ++t) {
    const _Float16* APc = (t & 1) ? AP1 : AP0;
    _Float16* APn       = (t & 1) ? AP0 : AP1;
    const _Float16* ACc = (t & 1) ? AC1 : AC0;
    _Float16* ACn       = (t & 1) ? AC0 : AC1;
    float* ot = (t >= 8) ? out + (size_t)(t - 8) * 1048576 : (float*)nullptr;
    k_step<<<dim3(768), blk256, 0, stream>>>(Q + (size_t)t * 1048576, APc,
                                             ACc, APn, ACn, Wrf, Wcf, bias_c,
                                             Pst, Cst, ot);
  }
}